// Round 1
// baseline (1308.542 us; speedup 1.0000x reference)
//
#include <hip/hip_runtime.h>
#include <hip/hip_bf16.h>

// Problem constants (from reference): B=16, C=8, T=4096, L=512, K=32, SEG=128.
// out[b,c,k,l] = sum_s x[b,c,k*SEG+s,l] * w[s]
// Flat: x offset for block bid=(b*C+c)*K+k is bid*SEG*L + s*L + l;
//       out offset is bid*L + l.

#define SEG 128
#define LDIM 512
#define L4 (LDIM / 4)   // 128 float4 per row

__global__ __launch_bounds__(128) void splitter_kernel(
    const float* __restrict__ x,
    const float* __restrict__ w,
    float* __restrict__ out)
{
    const int bid = blockIdx.x;       // 0 .. B*C*K-1 (4096)
    const int t   = threadIdx.x;      // 0 .. 127 : which float4 of the L row

    // Base pointer for this block's segment, as float4.
    const float4* __restrict__ xb =
        reinterpret_cast<const float4*>(x) + (size_t)bid * SEG * L4 + t;

    float4 acc = make_float4(0.f, 0.f, 0.f, 0.f);

#pragma unroll 8
    for (int s = 0; s < SEG; ++s) {
        const float ws = w[s];            // wave-uniform -> scalar load
        const float4 v = xb[(size_t)s * L4];
        acc.x += v.x * ws;
        acc.y += v.y * ws;
        acc.z += v.z * ws;
        acc.w += v.w * ws;
    }

    reinterpret_cast<float4*>(out)[(size_t)bid * L4 + t] = acc;
}

extern "C" void kernel_launch(void* const* d_in, const int* in_sizes, int n_in,
                              void* d_out, int out_size, void* d_ws, size_t ws_size,
                              hipStream_t stream)
{
    const float* x = (const float*)d_in[0];   // [B,C,T,L] fp32
    const float* w = (const float*)d_in[1];   // [SEG] fp32
    float* out     = (float*)d_out;           // [B,C,K,L] fp32

    const int nblocks = out_size / LDIM;      // B*C*K = 4096
    splitter_kernel<<<nblocks, 128, 0, stream>>>(x, w, out);
}